// Round 1
// baseline (3471.895 us; speedup 1.0000x reference)
//
#include <hip/hip_runtime.h>
#include <hip/hip_bf16.h>
#include <stdint.h>

// ---------------------------------------------------------------------------
// QuantMistralMLP: fake_quant(x) -> gate/up GEMM -> SwiGLU -> fake_quant ->
// down GEMM.  All GEMMs on bf16 MFMA with exact-int8 A operand (q exact in
// bf16, per-row scale applied in epilogue).  gate/up weights split hi+lo
// (2-pass, ~fp32 accuracy); w_down single bf16 pass (linear error only).
// ---------------------------------------------------------------------------

typedef float  f32x4  __attribute__((ext_vector_type(4)));
typedef __bf16 bf16x8 __attribute__((ext_vector_type(8)));
typedef unsigned short ushort4v __attribute__((ext_vector_type(4)));

typedef __attribute__((address_space(1))) void* as1v;
typedef __attribute__((address_space(3))) void* as3v;
#define GLOAD_LDS16(g, l) __builtin_amdgcn_global_load_lds((as1v)(g), (as3v)(l), 16, 0, 0)
#define MFMA16(a, b, c) __builtin_amdgcn_mfma_f32_16x16x32_bf16((a), (b), (c), 0, 0, 0)

// XOR-swizzled byte offset inside a [rows][64] bf16 tile (128B rows, 8x16B chunks).
static __device__ __forceinline__ unsigned swz_off(unsigned row, unsigned chunk) {
  return (row << 7) | (((chunk ^ (row & 7u)) & 7u) << 4);
}

static __device__ __forceinline__ bf16x8 ld_frag(const __bf16* base, unsigned row, unsigned chunk) {
  return *(const bf16x8*)((const char*)base + swz_off(row, chunk));
}

static __device__ __forceinline__ void split_store(__bf16* hb, __bf16* lb, unsigned row,
                                                   unsigned chunk, float4 a, float4 b) {
  float xs[8] = {a.x, a.y, a.z, a.w, b.x, b.y, b.z, b.w};
  bf16x8 h, l;
#pragma unroll
  for (int e = 0; e < 8; ++e) {
    __bf16 hh = (__bf16)xs[e];
    float hf = __builtin_bit_cast(float, (unsigned)__builtin_bit_cast(unsigned short, hh) << 16);
    h[e] = hh;
    l[e] = (__bf16)(xs[e] - hf);
  }
  unsigned o = swz_off(row, chunk);
  *(bf16x8*)((char*)hb + o) = h;
  *(bf16x8*)((char*)lb + o) = l;
}

static __device__ __forceinline__ void store_hi(__bf16* hb, unsigned row, unsigned chunk,
                                                float4 a, float4 b) {
  float xs[8] = {a.x, a.y, a.z, a.w, b.x, b.y, b.z, b.w};
  bf16x8 h;
#pragma unroll
  for (int e = 0; e < 8; ++e) h[e] = (__bf16)xs[e];
  *(bf16x8*)((char*)hb + swz_off(row, chunk)) = h;
}

// ---------------------------------------------------------------------------
// Kernel 1: per-token fake-quant of hidden_states. Row = 4096 fp32.
// Writes q (bf16, exact ints in [-128,127]) and xscale (fp32 per row).
// ---------------------------------------------------------------------------
__global__ __launch_bounds__(256) void quantx_kernel(const float* __restrict__ x,
                                                     __bf16* __restrict__ q,
                                                     float* __restrict__ xscale) {
  const unsigned row = blockIdx.x, t = threadIdx.x;
  const float4* src = (const float4*)(x + (size_t)row * 4096);
  float4 v[4];
  float mx = 0.f;
#pragma unroll
  for (int j = 0; j < 4; ++j) {
    v[j] = src[j * 256 + t];
    mx = fmaxf(mx, fmaxf(fmaxf(fabsf(v[j].x), fabsf(v[j].y)), fmaxf(fabsf(v[j].z), fabsf(v[j].w))));
  }
#pragma unroll
  for (int o = 32; o > 0; o >>= 1) mx = fmaxf(mx, __shfl_xor(mx, o));
  __shared__ float smax[4];
  if ((t & 63u) == 0) smax[t >> 6] = mx;
  __syncthreads();
  mx = fmaxf(fmaxf(smax[0], smax[1]), fmaxf(smax[2], smax[3]));
  const float sc = fmaxf(mx * (1.f / 127.f), 1e-8f);
  const float rs = 1.f / sc;
  if (t == 0) xscale[row] = sc;
  ushort4v* dst = (ushort4v*)(q + (size_t)row * 4096);
#pragma unroll
  for (int j = 0; j < 4; ++j) {
    float qv[4] = {v[j].x, v[j].y, v[j].z, v[j].w};
    ushort4v o4;
#pragma unroll
    for (int e = 0; e < 4; ++e) {
      float qq = rintf(qv[e] * rs);
      qq = fminf(fmaxf(qq, -128.f), 127.f);
      o4[e] = __builtin_bit_cast(unsigned short, (__bf16)qq);
    }
    dst[j * 256 + t] = o4;
  }
}

// ---------------------------------------------------------------------------
// Kernel 2: fused gate+up GEMM + SwiGLU.
// C tile 128(M) x 64(I), BK=64, 4 waves (2x2), each wave 64x32 for both g,u.
// A (q bf16) via global_load_lds w/ pre-swizzled source; B (fp32 weights)
// reg-staged, split hi/lo, XOR-swizzled ds_write_b128.
// ---------------------------------------------------------------------------
__global__ __launch_bounds__(256, 2) void gemm_gateup(const __bf16* __restrict__ q,
                                                      const float* __restrict__ wg,
                                                      const float* __restrict__ wu,
                                                      const float* __restrict__ xscale,
                                                      float* __restrict__ inter) {
  const unsigned H = 4096, I = 14336;
  __shared__ __align__(16) __bf16 sA[128 * 64];
  __shared__ __align__(16) __bf16 sGh[64 * 64], sGl[64 * 64], sUh[64 * 64], sUl[64 * 64];

  const unsigned t = threadIdx.x, bid = blockIdx.x;
  const unsigned mt = bid & 31u, it = bid >> 5;    // M fastest: weight panel streams once
  const unsigned m0 = mt * 128, i0 = it * 64;
  const unsigned w = t >> 6, lane = t & 63u, lr = lane & 15u, lh = lane >> 4;
  const unsigned wm = w >> 1, wn = w & 1u;

  f32x4 accg[4][2] = {};
  f32x4 accu[4][2] = {};

  const unsigned brow = t >> 2, bc0 = (t & 3u) * 16;  // B staging: 4 thr/row, 16 fp32 each
  const float* gptr = wg + (size_t)(i0 + brow) * H + bc0;
  const float* uptr = wu + (size_t)(i0 + brow) * H + bc0;

  for (unsigned kt = 0; kt < 64; ++kt) {
    const unsigned k0 = kt * 64;
    __syncthreads();
    // --- stage A: 128x64 bf16 via global_load_lds, source pre-swizzled ---
#pragma unroll
    for (unsigned s = 0; s < 4; ++s) {
      unsigned slot = s * 256 + t, row = slot >> 3, c = slot & 7u, gc = c ^ (row & 7u);
      const __bf16* gp = q + (size_t)(m0 + row) * H + k0 + gc * 8;
      GLOAD_LDS16(gp, (char*)sA + s * 4096 + (t & ~63u) * 16);
    }
    // --- stage B: 2x 64x64 fp32 -> hi/lo bf16, swizzled ds_write ---
    {
      float4 vg[4], vu[4];
#pragma unroll
      for (int j = 0; j < 4; ++j) {
        vg[j] = *(const float4*)(gptr + k0 + 4 * j);
        vu[j] = *(const float4*)(uptr + k0 + 4 * j);
      }
      split_store(sGh, sGl, brow, (bc0 >> 3) + 0, vg[0], vg[1]);
      split_store(sGh, sGl, brow, (bc0 >> 3) + 1, vg[2], vg[3]);
      split_store(sUh, sUl, brow, (bc0 >> 3) + 0, vu[0], vu[1]);
      split_store(sUh, sUl, brow, (bc0 >> 3) + 1, vu[2], vu[3]);
    }
    __syncthreads();
    // --- compute: 64 MFMA per wave per K-step ---
#pragma unroll
    for (unsigned ks = 0; ks < 2; ++ks) {
      bf16x8 a[4];
#pragma unroll
      for (int i = 0; i < 4; ++i) a[i] = ld_frag(sA, wm * 64 + i * 16 + lr, ks * 4 + lh);
#pragma unroll
      for (int n = 0; n < 2; ++n) {
        const unsigned rr = wn * 32 + n * 16 + lr, ck = ks * 4 + lh;
        bf16x8 gh = ld_frag(sGh, rr, ck), gl = ld_frag(sGl, rr, ck);
        bf16x8 uh = ld_frag(sUh, rr, ck), ul = ld_frag(sUl, rr, ck);
#pragma unroll
        for (int i = 0; i < 4; ++i) {
          accg[i][n] = MFMA16(a[i], gh, accg[i][n]);
          accg[i][n] = MFMA16(a[i], gl, accg[i][n]);
          accu[i][n] = MFMA16(a[i], uh, accu[i][n]);
          accu[i][n] = MFMA16(a[i], ul, accu[i][n]);
        }
      }
    }
  }
  // --- epilogue: apply x-scale, SwiGLU, write inter (fp32) ---
#pragma unroll
  for (int i = 0; i < 4; ++i) {
#pragma unroll
    for (int r = 0; r < 4; ++r) {
      const unsigned grow = m0 + wm * 64 + i * 16 + lh * 4 + r;
      const float xs = xscale[grow];
#pragma unroll
      for (int n = 0; n < 2; ++n) {
        const unsigned gcol = i0 + wn * 32 + n * 16 + lr;
        const float g = accg[i][n][r] * xs;
        const float u = accu[i][n][r] * xs;
        const float sil = g / (1.f + __expf(-g));
        inter[(size_t)grow * I + gcol] = sil * u;
      }
    }
  }
}

// ---------------------------------------------------------------------------
// Kernel 3: per-token fake-quant of inter (row = 14336 fp32, held in regs).
// ---------------------------------------------------------------------------
__global__ __launch_bounds__(256) void quant2_kernel(const float* __restrict__ inter,
                                                     __bf16* __restrict__ q2,
                                                     float* __restrict__ scale2) {
  const unsigned row = blockIdx.x, t = threadIdx.x;
  const float4* src = (const float4*)(inter + (size_t)row * 14336);
  float4 v[14];
  float mx = 0.f;
#pragma unroll
  for (int j = 0; j < 14; ++j) {
    v[j] = src[j * 256 + t];
    mx = fmaxf(mx, fmaxf(fmaxf(fabsf(v[j].x), fabsf(v[j].y)), fmaxf(fabsf(v[j].z), fabsf(v[j].w))));
  }
#pragma unroll
  for (int o = 32; o > 0; o >>= 1) mx = fmaxf(mx, __shfl_xor(mx, o));
  __shared__ float smax[4];
  if ((t & 63u) == 0) smax[t >> 6] = mx;
  __syncthreads();
  mx = fmaxf(fmaxf(smax[0], smax[1]), fmaxf(smax[2], smax[3]));
  const float sc = fmaxf(mx * (1.f / 127.f), 1e-8f);
  const float rs = 1.f / sc;
  if (t == 0) scale2[row] = sc;
  ushort4v* dst = (ushort4v*)(q2 + (size_t)row * 14336);
#pragma unroll
  for (int j = 0; j < 14; ++j) {
    float qv[4] = {v[j].x, v[j].y, v[j].z, v[j].w};
    ushort4v o4;
#pragma unroll
    for (int e = 0; e < 4; ++e) {
      float qq = rintf(qv[e] * rs);
      qq = fminf(fmaxf(qq, -128.f), 127.f);
      o4[e] = __builtin_bit_cast(unsigned short, (__bf16)qq);
    }
    dst[j * 256 + t] = o4;
  }
}

// ---------------------------------------------------------------------------
// Kernel 4: down GEMM. C tile 128(M) x 128(H), BK=64, 4 waves each 64x64.
// A = q2 (bf16 exact) via global_load_lds; B = w_down fp32 -> bf16 hi only.
// ---------------------------------------------------------------------------
__global__ __launch_bounds__(256, 2) void gemm_down(const __bf16* __restrict__ q2,
                                                    const float* __restrict__ wd,
                                                    const float* __restrict__ s2,
                                                    float* __restrict__ out) {
  const unsigned K = 14336, N = 4096;
  __shared__ __align__(16) __bf16 sA[128 * 64];
  __shared__ __align__(16) __bf16 sB[128 * 64];

  const unsigned t = threadIdx.x, bid = blockIdx.x;
  const unsigned mt = bid & 31u, ht = bid >> 5;    // M fastest: w_down panel streams once
  const unsigned m0 = mt * 128, h0 = ht * 128;
  const unsigned w = t >> 6, lane = t & 63u, lr = lane & 15u, lh = lane >> 4;
  const unsigned wm = w >> 1, wn = w & 1u;

  f32x4 acc[4][4] = {};

  const unsigned brow = t >> 1, bc0 = (t & 1u) * 32;  // B staging: 2 thr/row, 32 fp32 each
  const float* bptr = wd + (size_t)(h0 + brow) * K + bc0;

  for (unsigned kt = 0; kt < 224; ++kt) {
    const unsigned k0 = kt * 64;
    __syncthreads();
#pragma unroll
    for (unsigned s = 0; s < 4; ++s) {
      unsigned slot = s * 256 + t, row = slot >> 3, c = slot & 7u, gc = c ^ (row & 7u);
      const __bf16* gp = q2 + (size_t)(m0 + row) * K + k0 + gc * 8;
      GLOAD_LDS16(gp, (char*)sA + s * 4096 + (t & ~63u) * 16);
    }
    {
      float4 v[8];
#pragma unroll
      for (int j = 0; j < 8; ++j) v[j] = *(const float4*)(bptr + k0 + 4 * j);
#pragma unroll
      for (int j2 = 0; j2 < 4; ++j2) store_hi(sB, brow, (bc0 >> 3) + j2, v[2 * j2], v[2 * j2 + 1]);
    }
    __syncthreads();
#pragma unroll
    for (unsigned ks = 0; ks < 2; ++ks) {
      bf16x8 a[4], b[4];
#pragma unroll
      for (int i = 0; i < 4; ++i) a[i] = ld_frag(sA, wm * 64 + i * 16 + lr, ks * 4 + lh);
#pragma unroll
      for (int n = 0; n < 4; ++n) b[n] = ld_frag(sB, wn * 64 + n * 16 + lr, ks * 4 + lh);
#pragma unroll
      for (int i = 0; i < 4; ++i)
#pragma unroll
        for (int n = 0; n < 4; ++n) acc[i][n] = MFMA16(a[i], b[n], acc[i][n]);
    }
  }
#pragma unroll
  for (int i = 0; i < 4; ++i) {
#pragma unroll
    for (int r = 0; r < 4; ++r) {
      const unsigned grow = m0 + wm * 64 + i * 16 + lh * 4 + r;
      const float sc = s2[grow];
#pragma unroll
      for (int n = 0; n < 4; ++n) {
        const unsigned gcol = h0 + wn * 64 + n * 16 + lr;
        out[(size_t)grow * N + gcol] = acc[i][n][r] * sc;
      }
    }
  }
}

// ---------------------------------------------------------------------------
extern "C" void kernel_launch(void* const* d_in, const int* in_sizes, int n_in,
                              void* d_out, int out_size, void* d_ws, size_t ws_size,
                              hipStream_t stream) {
  const float* x  = (const float*)d_in[0];
  const float* wg = (const float*)d_in[1];
  const float* wu = (const float*)d_in[2];
  const float* wd = (const float*)d_in[3];
  float* out = (float*)d_out;
  char* ws = (char*)d_ws;

  const size_t M = 4096, H = 4096, I = 14336;
  __bf16* q = (__bf16*)ws;
  size_t off = M * H * sizeof(__bf16);               // 32 MB
  float* xscale = (float*)(ws + off); off += M * sizeof(float);
  float* inter  = (float*)(ws + off); off += M * I * sizeof(float);   // 229 MB
  __bf16* q2    = (__bf16*)(ws + off); off += M * I * sizeof(__bf16); // 114 MB
  float* scale2 = (float*)(ws + off);

  quantx_kernel<<<4096, 256, 0, stream>>>(x, q, xscale);
  gemm_gateup<<<7168, 256, 0, stream>>>(q, wg, wu, xscale, inter);
  quant2_kernel<<<4096, 256, 0, stream>>>(inter, q2, scale2);
  gemm_down<<<1024, 256, 0, stream>>>(q2, wd, scale2, out);
}